// Round 1
// baseline (91.594 us; speedup 1.0000x reference)
//
#include <hip/hip_runtime.h>
#include <math.h>

// Levinson-Durbin: solve R a = -r1 for each batch, K = sqrt(r0 + r1.a).
// One thread per batch; arrays fully unrolled into registers.

constexpr int M  = 64;
constexpr int EL = M + 1;   // 65 floats per row
constexpr int BT = 128;     // threads (=batches) per block

__global__ __launch_bounds__(BT) void levinson_kernel(const float* __restrict__ rin,
                                                      float* __restrict__ out,
                                                      int B) {
  __shared__ float smem[BT * EL];   // 33,280 B
  const int tid = threadIdx.x;
  const int b0  = blockIdx.x * BT;
  const int nb  = min(BT, B - b0);
  const int nf  = nb * EL;
  const size_t base = (size_t)b0 * EL;

  // ---- coalesced stage-in: global float4 -> LDS ----
  {
    const int n4 = nf >> 2;
    const float4* in4 = reinterpret_cast<const float4*>(rin + base); // base*4 % 16 == 0
    float4* s4 = reinterpret_cast<float4*>(smem);
    for (int i = tid; i < n4; i += BT) s4[i] = in4[i];
    for (int i = (n4 << 2) + tid; i < nf; i += BT) smem[i] = rin[base + i];
  }
  __syncthreads();

  float K = 0.f;
  float a[M + 1];   // a[1..M]
  if (tid < nb) {
    float r[EL];
#pragma unroll
    for (int i = 0; i < EL; ++i) r[i] = smem[tid * EL + i];  // stride 65 words: conflict-free

    float Eacc = r[0];
#pragma unroll
    for (int m = 1; m <= M; ++m) {
      // acc = r[m] + sum_{j=1}^{m-1} a[j] * r[m-j]   (4 accumulators for ILP)
      float s[4] = {0.f, 0.f, 0.f, 0.f};
#pragma unroll
      for (int j = 1; j <= m - 1; ++j)
        s[j & 3] = fmaf(a[j], r[m - j], s[j & 3]);
      const float acc = r[m] + ((s[0] + s[1]) + (s[2] + s[3]));
      const float k = -acc / Eacc;          // IEEE divide (precision)
      // a[j] += k * a[m-j], pairwise (independent FMAs)
#pragma unroll
      for (int j = 1; 2 * j < m; ++j) {
        const float aj = a[j], amj = a[m - j];
        a[j]     = fmaf(k, amj, aj);
        a[m - j] = fmaf(k, aj, amj);
      }
      if ((m & 1) == 0) {
        const float ah = a[m >> 1];
        a[m >> 1] = fmaf(k, ah, ah);
      }
      a[m] = k;
      Eacc = fmaf(-k * k, Eacc, Eacc);      // E *= (1 - k^2)
    }
    K = sqrtf(Eacc);
  }

  // own-row LDS writes race with nothing (each thread reads/writes only its row)
  if (tid < nb) {
    smem[tid * EL] = K;
#pragma unroll
    for (int j = 1; j <= M; ++j) smem[tid * EL + j] = a[j];
  }
  __syncthreads();

  // ---- coalesced stage-out: LDS -> global float4 ----
  {
    const int n4 = nf >> 2;
    const float4* s4 = reinterpret_cast<const float4*>(smem);
    float4* out4 = reinterpret_cast<float4*>(out + base);
    for (int i = tid; i < n4; i += BT) out4[i] = s4[i];
    for (int i = (n4 << 2) + tid; i < nf; i += BT) out[base + i] = smem[i];
  }
}

extern "C" void kernel_launch(void* const* d_in, const int* in_sizes, int n_in,
                              void* d_out, int out_size, void* d_ws, size_t ws_size,
                              hipStream_t stream) {
  const float* r = (const float*)d_in[0];
  float* out = (float*)d_out;
  const int B = in_sizes[0] / EL;          // 65536
  const int blocks = (B + BT - 1) / BT;    // 512
  levinson_kernel<<<blocks, BT, 0, stream>>>(r, out, B);
}